// Round 16
// baseline (770.814 us; speedup 1.0000x reference)
//
#include <hip/hip_runtime.h>
#include <hip/hip_bf16.h>
#include <hip/hip_fp8.h>
#include <math.h>

#define IGNORE_INDEX (-100)

static constexpr int Dc = 1024, Vc = 128000;
static constexpr int Mrows = 2048;        // B*S
static constexpr int Kdim = 1024;
static constexpr int BK = 32;             // fp8: 32 elems = 32 B rows
static constexpr int NT = Kdim / BK;      // 32 K-tiles
static constexpr int NCHUNK = Vc / 64;    // 2000 partial chunks per row

typedef float f32x4_t __attribute__((ext_vector_type(4)));

// ---------------- cast fp32 -> fp8 e4m3 (OCP), 4 elems/thread/iter ----------
__global__ void cast_f32_fp8(const float* __restrict__ in, uchar4* __restrict__ out,
                             size_t n4) {
  size_t i = (size_t)blockIdx.x * blockDim.x + threadIdx.x;
  size_t stride = (size_t)gridDim.x * blockDim.x;
  for (; i < n4; i += stride) {
    float4 v = reinterpret_cast<const float4*>(in)[i];
    uchar4 o;
    o.x = __hip_fp8_e4m3(v.x).__x;
    o.y = __hip_fp8_e4m3(v.y).__x;
    o.z = __hip_fp8_e4m3(v.z).__x;
    o.w = __hip_fp8_e4m3(v.w).__x;
    out[i] = o;
  }
}

// ---------------- target logits: fp32 dot(hidden[r], weight[t[r]]) — exact ----
__global__ void tgt_kernel(const float* __restrict__ hidden, const float* __restrict__ weight,
                           const int* __restrict__ targets, float* __restrict__ tgt) {
  int row = blockIdx.x * 4 + (threadIdx.x >> 6);
  int lane = threadIdx.x & 63;
  if (row >= Mrows) return;
  int t = targets[row];
  float sum = 0.f;
  if (t != IGNORE_INDEX) {
    const float* h = hidden + (size_t)row * Kdim;
    const float* wv = weight + (size_t)t * Kdim;
    for (int k = lane * 4; k < Kdim; k += 64 * 4) {
      float4 a = *reinterpret_cast<const float4*>(h + k);
      float4 b = *reinterpret_cast<const float4*>(wv + k);
      sum += a.x * b.x + a.y * b.y + a.z * b.z + a.w * b.w;
    }
  }
  #pragma unroll
  for (int d = 1; d < 64; d <<= 1) sum += __shfl_xor(sum, d);
  if (lane == 0) tgt[row] = sum;
}

// -- 128x256 8-wave 2-BLOCK/CU ring-3 FP8 GEMM + fused partial LSE -----------
// R15 lesson: MfmaUtil pinned ~40% across 4 schedules -> LDS-pipe bytes/FLOP
// bound, not scheduling. fp8 e4m3 halves operand bytes: ds_read_b64 frags,
// 12KB/tile staged. At BK=32 fp8 rows are 32B and each wave frag read is a
// CONTIGUOUS 512B block -> conflict-free by construction, NO swizzle.
// Staging: 2 loads/thread/tile, wave-uniform (A chunk tid&255 duplicated --
// identical-data WAW, benign; B chunk tid) -> counted vmcnt(2) safe (R8 rule:
// uniform counts + identical per-thread issue order + in-order retirement).
// MFMA: mfma_f32_16x16x32_fp8_fp8 (same rate as bf16, m11; operands i64).
#define MFMA_FP8(A, B, C) __builtin_amdgcn_mfma_f32_16x16x32_fp8_fp8((A), (B), (C), 0, 0, 0)
#define GLDS(g, l) __builtin_amdgcn_global_load_lds( \
    (const __attribute__((address_space(1))) void*)(g), \
    (__attribute__((address_space(3))) void*)(l), 16, 0, 0)

__global__ __launch_bounds__(512, 4) void gemm_lse_fp8(const uchar* __restrict__ A8,
                                                       const uchar* __restrict__ B8,
                                                       float2* __restrict__ part) {
  __shared__ uchar lds[3][12288];      // [ring][A(128x32B)=4KB | B(256x32B)=8KB]
  const int tid = threadIdx.x;
  const int wid = tid >> 6, lane = tid & 63;
  const int wr = wid >> 2, wc = wid & 3;        // 2M x 4N wave grid, wave = 64x64 out
  const int l15 = lane & 15, l16 = lane >> 4;
  const int bid = blockIdx.x;
  const int mb = bid & 15;             // 16 M-blocks share one B panel
  const int nb = bid >> 4;             // 0..499

  // staging sources (byte addressing; fp8 row = 1024 B)
  const int ca = tid & 255;            // A chunk (duplicated across tid>=256)
  const uchar* gA = A8 + (size_t)(mb * 128) * 1024;
  const uchar* gB = B8 + (size_t)(nb * 256) * 1024;
  const uchar* sgA = gA + (size_t)(ca >> 1) * 1024 + (ca & 1) * 16;
  const uchar* sgB = gB + (size_t)(tid >> 1) * 1024 + (tid & 1) * 16;

  // read-side: A region rows 32B; frag base contiguous 512B per wave read
  const int aBase = (wr * 64 + l15) * 32 + l16 * 8;   // + mi*512 per frag
  const int bBase = (wc * 64 + l15) * 32 + l16 * 8;   // + ni*512 (B region +4096)

  f32x4_t acc[4][4];
  #pragma unroll
  for (int i = 0; i < 4; ++i)
    #pragma unroll
    for (int j = 0; j < 4; ++j)
      acc[i][j] = (f32x4_t){0.f, 0.f, 0.f, 0.f};

  #define STAGE(bufp, k0) do { \
    GLDS(sgA + (k0), (bufp) + ca * 16); \
    GLDS(sgB + (k0), (bufp) + 4096 + tid * 16); \
  } while (0)

  // prologue: tiles 0,1 staged; vmcnt(2) -> tile0's 2 loads retired
  STAGE(lds[0], 0);
  STAGE(lds[1], BK);
  asm volatile("s_waitcnt vmcnt(2)" ::: "memory");
  __builtin_amdgcn_s_barrier();

  int cur = 0;
  for (int t = 0; t < NT; ++t) {
    if (t + 2 < NT) {
      int stg = cur + 2; if (stg >= 3) stg -= 3;
      STAGE(lds[stg], (t + 2) * BK);
    }
    const uchar* Ar = lds[cur];
    const uchar* Br = lds[cur] + 4096;
    long a[4], b[4];
    #pragma unroll
    for (int mi = 0; mi < 4; ++mi)
      a[mi] = *reinterpret_cast<const long*>(Ar + aBase + mi * 512);
    #pragma unroll
    for (int ni = 0; ni < 4; ++ni)
      b[ni] = *reinterpret_cast<const long*>(Br + bBase + ni * 512);
    __builtin_amdgcn_s_setprio(1);
    #pragma unroll
    for (int mi = 0; mi < 4; ++mi)
      #pragma unroll
      for (int ni = 0; ni < 4; ++ni)
        acc[mi][ni] = MFMA_FP8(a[mi], b[ni], acc[mi][ni]);
    __builtin_amdgcn_s_setprio(0);
    if (t + 1 < NT) {
      if (t + 2 < NT) asm volatile("s_waitcnt vmcnt(2)" ::: "memory");
      else            asm volatile("s_waitcnt vmcnt(0)" ::: "memory");
      __builtin_amdgcn_s_barrier();
    }
    cur = cur + 1; if (cur >= 3) cur = 0;
  }
  #undef STAGE

  // fused partial-LSE epilogue. acc[mi][ni][j]: row = wr*64+mi*16+l16*4+j,
  // col = wc*64+ni*16+l15 (m89 C/D layout; dtype-independent m121-128)
  const int chunk = nb * 4 + wc;
  #pragma unroll
  for (int mi = 0; mi < 4; ++mi) {
    #pragma unroll
    for (int j = 0; j < 4; ++j) {
      float v0 = acc[mi][0][j], v1 = acc[mi][1][j], v2 = acc[mi][2][j], v3 = acc[mi][3][j];
      float mloc = fmaxf(fmaxf(v0, v1), fmaxf(v2, v3));
      #pragma unroll
      for (int d = 1; d < 16; d <<= 1) mloc = fmaxf(mloc, __shfl_xor(mloc, d));
      float sloc = __expf(v0 - mloc) + __expf(v1 - mloc) +
                   __expf(v2 - mloc) + __expf(v3 - mloc);
      #pragma unroll
      for (int d = 1; d < 16; d <<= 1) sloc += __shfl_xor(sloc, d);
      if (l15 == 0) {
        int grow = mb * 128 + wr * 64 + mi * 16 + l16 * 4 + j;
        part[(size_t)grow * NCHUNK + chunk] = make_float2(mloc, sloc);
      }
    }
  }
}

// ---------------- per-row merge of partials -> nll[row] ----------------
__device__ __forceinline__ void merge_ms(float& m, float& s, float m2, float s2) {
  if (m2 > m) { s = s * __expf(m - m2) + s2; m = m2; }
  else        { s += s2 * __expf(m2 - m); }
}

__global__ void lse_reduce(const float2* __restrict__ part, const float* __restrict__ tgt,
                           const int* __restrict__ targets, float* __restrict__ nll) {
  int row = blockIdx.x;
  const float2* p = part + (size_t)row * NCHUNK;
  float m = -INFINITY, s = 0.f;
  for (int c = threadIdx.x; c < NCHUNK; c += blockDim.x) {
    float2 v = p[c];
    merge_ms(m, s, v.x, v.y);
  }
  #pragma unroll
  for (int d = 1; d < 64; d <<= 1) {
    float m2 = __shfl_xor(m, d), s2 = __shfl_xor(s, d);
    merge_ms(m, s, m2, s2);
  }
  __shared__ float sm[4], ss[4];
  int wid = threadIdx.x >> 6, lane = threadIdx.x & 63;
  if (lane == 0) { sm[wid] = m; ss[wid] = s; }
  __syncthreads();
  if (threadIdx.x == 0) {
    #pragma unroll
    for (int w2 = 1; w2 < 4; ++w2) merge_ms(m, s, sm[w2], ss[w2]);
    int t = targets[row];
    float out = 0.f;
    if (t != IGNORE_INDEX) out = m + logf(s) - tgt[row];
    nll[row] = out;
  }
}

// ---------------- final scalar: sum(nll)/count ----------------
__global__ void final_kernel(const float* __restrict__ nll, const int* __restrict__ targets,
                             float* __restrict__ out) {
  float sum = 0.f, cnt = 0.f;
  for (int i = threadIdx.x; i < Mrows; i += 64) {
    sum += nll[i];
    cnt += (targets[i] != IGNORE_INDEX) ? 1.f : 0.f;
  }
  #pragma unroll
  for (int d = 1; d < 64; d <<= 1) {
    sum += __shfl_xor(sum, d);
    cnt += __shfl_xor(cnt, d);
  }
  if (threadIdx.x == 0)
    out[0] = (cnt == 0.f) ? sum : sum / fmaxf(cnt, 1.f);
}

extern "C" void kernel_launch(void* const* d_in, const int* in_sizes, int n_in,
                              void* d_out, int out_size, void* d_ws, size_t ws_size,
                              hipStream_t stream) {
  const float* hidden = (const float*)d_in[0];   // [2,1024,1024] f32
  const float* weight = (const float*)d_in[1];   // [128000,1024] f32
  const int* targets  = (const int*)d_in[2];     // [2,1024] i32
  float* out = (float*)d_out;

  char* ws = (char*)d_ws;
  size_t off = 0;
  uchar* w8 = (uchar*)(ws + off); off += (size_t)Vc * Dc;                  // 128 MB
  uchar* h8 = (uchar*)(ws + off); off += (size_t)Mrows * Dc;               // 2 MB
  float2* part = (float2*)(ws + off); off += (size_t)Mrows * NCHUNK * sizeof(float2); // 32 MB
  float* tgt = (float*)(ws + off); off += Mrows * sizeof(float);
  float* nll = (float*)(ws + off); off += Mrows * sizeof(float);
  (void)ws_size; (void)in_sizes; (void)n_in; (void)out_size;

  cast_f32_fp8<<<2048, 256, 0, stream>>>(weight, (uchar4*)w8, (size_t)Vc * Dc / 4);
  cast_f32_fp8<<<256, 256, 0, stream>>>(hidden, (uchar4*)h8, (size_t)Mrows * Dc / 4);
  tgt_kernel<<<Mrows / 4, 256, 0, stream>>>(hidden, weight, targets, tgt);

  gemm_lse_fp8<<<8000, 512, 0, stream>>>(h8, w8, part);  // mb=bid&15, nb=bid>>4

  lse_reduce<<<Mrows, 256, 0, stream>>>(part, tgt, targets, nll);
  final_kernel<<<1, 64, 0, stream>>>(nll, targets, out);
}

// Round 17
// 641.409 us; speedup vs baseline: 1.2018x; 1.2018x over previous
//
#include <hip/hip_runtime.h>
#include <hip/hip_bf16.h>
#include <hip/hip_fp8.h>
#include <math.h>

#define IGNORE_INDEX (-100)

static constexpr int Dc = 1024, Vc = 128000;
static constexpr int Mrows = 2048;        // B*S
static constexpr int Kdim = 1024;
static constexpr int BK = 32;             // fp8: 32 elems = 32 B rows
static constexpr int NT = Kdim / BK;      // 32 K-tiles
static constexpr int NCHUNK = Vc / 64;    // 2000 partial chunks per row

typedef float f32x4_t __attribute__((ext_vector_type(4)));

// ---------------- cast fp32 -> fp8 e4m3 (OCP), 4 elems/thread/iter ----------
__global__ void cast_f32_fp8(const float* __restrict__ in, uchar4* __restrict__ out,
                             size_t n4) {
  size_t i = (size_t)blockIdx.x * blockDim.x + threadIdx.x;
  size_t stride = (size_t)gridDim.x * blockDim.x;
  for (; i < n4; i += stride) {
    float4 v = reinterpret_cast<const float4*>(in)[i];
    uchar4 o;
    o.x = __hip_fp8_e4m3(v.x).__x;
    o.y = __hip_fp8_e4m3(v.y).__x;
    o.z = __hip_fp8_e4m3(v.z).__x;
    o.w = __hip_fp8_e4m3(v.w).__x;
    out[i] = o;
  }
}

// ---------------- target logits: fp32 dot(hidden[r], weight[t[r]]) — exact ----
__global__ void tgt_kernel(const float* __restrict__ hidden, const float* __restrict__ weight,
                           const int* __restrict__ targets, float* __restrict__ tgt) {
  int row = blockIdx.x * 4 + (threadIdx.x >> 6);
  int lane = threadIdx.x & 63;
  if (row >= Mrows) return;
  int t = targets[row];
  float sum = 0.f;
  if (t != IGNORE_INDEX) {
    const float* h = hidden + (size_t)row * Kdim;
    const float* wv = weight + (size_t)t * Kdim;
    for (int k = lane * 4; k < Kdim; k += 64 * 4) {
      float4 a = *reinterpret_cast<const float4*>(h + k);
      float4 b = *reinterpret_cast<const float4*>(wv + k);
      sum += a.x * b.x + a.y * b.y + a.z * b.z + a.w * b.w;
    }
  }
  #pragma unroll
  for (int d = 1; d < 64; d <<= 1) sum += __shfl_xor(sum, d);
  if (lane == 0) tgt[row] = sum;
}

// -- 128x256 8-wave 2-BLOCK/CU ring-3 FP8 GEMM + fused partial LSE -----------
// R16 lesson: fp8 ds_read_b64 on linear 32B rows = 4-way bank conflict
// (16-lane HW groups read an 8B column at 32B stride -> banks {0,8,16,24}
// only; SQ_LDS_BANK_CONFLICT 1.97e8). FIX: 16B-chunk swizzle
//   chunk' = chunk ^ ((row>>2)&1)
// applied as linear LDS dest + inverse-swizzled GLOBAL source (16B granules
// stay contiguous -> global_load_lds-compatible) + swizzled ds_read (rule #21).
// Hand-verified: lane group 0-15 banks = {0,8,16,24,4,12,20,28} x2 -> 2-way,
// which is FREE (m136: 1.02x). fp8 MFMA path + C/D layout validated by R16
// (passed, absmax~0). Staging: 2 uniform loads/thread/tile -> vmcnt(2) safe.
#define MFMA_FP8(A, B, C) __builtin_amdgcn_mfma_f32_16x16x32_fp8_fp8((A), (B), (C), 0, 0, 0)
#define GLDS(g, l) __builtin_amdgcn_global_load_lds( \
    (const __attribute__((address_space(1))) void*)(g), \
    (__attribute__((address_space(3))) void*)(l), 16, 0, 0)

__global__ __launch_bounds__(512, 4) void gemm_lse_fp8(const uchar* __restrict__ A8,
                                                       const uchar* __restrict__ B8,
                                                       float2* __restrict__ part) {
  __shared__ uchar lds[3][12288];      // [ring][A(128x32B)=4KB | B(256x32B)=8KB]
  const int tid = threadIdx.x;
  const int wid = tid >> 6, lane = tid & 63;
  const int wr = wid >> 2, wc = wid & 3;        // 2M x 4N wave grid, wave = 64x64 out
  const int l15 = lane & 15, l16 = lane >> 4;
  const int bid = blockIdx.x;
  const int mb = bid & 15;             // 16 M-blocks share one B panel
  const int nb = bid >> 4;             // 0..499

  // staging (byte addressing; fp8 K-row = 1024 B in global).
  // A: 256 LDS chunks; ca=tid&255 (duplicated across tid>=256 — identical WAW).
  //    row = ca>>1, chunkpos = ca&1, src chunk = chunkpos ^ ((row>>2)&1).
  const int ca = tid & 255;
  const int arow = ca >> 1;
  const int asrc = (ca & 1) ^ ((arow >> 2) & 1);
  // B: 512 LDS chunks; row = tid>>1, chunkpos = tid&1, src = ^ ((row>>2)&1).
  const int brow = tid >> 1;
  const int bsrc = (tid & 1) ^ ((brow >> 2) & 1);
  const uchar* gA = A8 + (size_t)(mb * 128) * 1024;
  const uchar* gB = B8 + (size_t)(nb * 256) * 1024;
  const uchar* sgA = gA + (size_t)arow * 1024 + asrc * 16;
  const uchar* sgB = gB + (size_t)brow * 1024 + bsrc * 16;

  // read-side swizzled offset: logical 8B slot l16 -> chunk l16>>1, sub l16&1;
  // chunk' = (l16>>1) ^ ((row>>2)&1); frag row bases are multiples of 16 ->
  // (row>>2)&1 = (l15>>2)&1 per lane.
  const int koff = ((((l16 >> 1) ^ ((l15 >> 2) & 1)) << 4) | ((l16 & 1) << 3));
  const int aBase = (wr * 64 + l15) * 32 + koff;   // + mi*512 per frag
  const int bBase = (wc * 64 + l15) * 32 + koff;   // + ni*512 (B region +4096)

  f32x4_t acc[4][4];
  #pragma unroll
  for (int i = 0; i < 4; ++i)
    #pragma unroll
    for (int j = 0; j < 4; ++j)
      acc[i][j] = (f32x4_t){0.f, 0.f, 0.f, 0.f};

  #define STAGE(bufp, k0) do { \
    GLDS(sgA + (k0), (bufp) + ca * 16); \
    GLDS(sgB + (k0), (bufp) + 4096 + tid * 16); \
  } while (0)

  // prologue: tiles 0,1 staged; vmcnt(2) -> tile0's 2 loads retired
  STAGE(lds[0], 0);
  STAGE(lds[1], BK);
  asm volatile("s_waitcnt vmcnt(2)" ::: "memory");
  __builtin_amdgcn_s_barrier();

  int cur = 0;
  for (int t = 0; t < NT; ++t) {
    if (t + 2 < NT) {
      int stg = cur + 2; if (stg >= 3) stg -= 3;
      STAGE(lds[stg], (t + 2) * BK);
    }
    const uchar* Ar = lds[cur];
    const uchar* Br = lds[cur] + 4096;
    long a[4], b[4];
    #pragma unroll
    for (int mi = 0; mi < 4; ++mi)
      a[mi] = *reinterpret_cast<const long*>(Ar + aBase + mi * 512);
    #pragma unroll
    for (int ni = 0; ni < 4; ++ni)
      b[ni] = *reinterpret_cast<const long*>(Br + bBase + ni * 512);
    __builtin_amdgcn_s_setprio(1);
    #pragma unroll
    for (int mi = 0; mi < 4; ++mi)
      #pragma unroll
      for (int ni = 0; ni < 4; ++ni)
        acc[mi][ni] = MFMA_FP8(a[mi], b[ni], acc[mi][ni]);
    __builtin_amdgcn_s_setprio(0);
    if (t + 1 < NT) {
      if (t + 2 < NT) asm volatile("s_waitcnt vmcnt(2)" ::: "memory");
      else            asm volatile("s_waitcnt vmcnt(0)" ::: "memory");
      __builtin_amdgcn_s_barrier();
    }
    cur = cur + 1; if (cur >= 3) cur = 0;
  }
  #undef STAGE

  // fused partial-LSE epilogue. acc[mi][ni][j]: row = wr*64+mi*16+l16*4+j,
  // col = wc*64+ni*16+l15 (m89 C/D layout; dtype-independent m121-128)
  const int chunk = nb * 4 + wc;
  #pragma unroll
  for (int mi = 0; mi < 4; ++mi) {
    #pragma unroll
    for (int j = 0; j < 4; ++j) {
      float v0 = acc[mi][0][j], v1 = acc[mi][1][j], v2 = acc[mi][2][j], v3 = acc[mi][3][j];
      float mloc = fmaxf(fmaxf(v0, v1), fmaxf(v2, v3));
      #pragma unroll
      for (int d = 1; d < 16; d <<= 1) mloc = fmaxf(mloc, __shfl_xor(mloc, d));
      float sloc = __expf(v0 - mloc) + __expf(v1 - mloc) +
                   __expf(v2 - mloc) + __expf(v3 - mloc);
      #pragma unroll
      for (int d = 1; d < 16; d <<= 1) sloc += __shfl_xor(sloc, d);
      if (l15 == 0) {
        int grow = mb * 128 + wr * 64 + mi * 16 + l16 * 4 + j;
        part[(size_t)grow * NCHUNK + chunk] = make_float2(mloc, sloc);
      }
    }
  }
}

// ---------------- per-row merge of partials -> nll[row] ----------------
__device__ __forceinline__ void merge_ms(float& m, float& s, float m2, float s2) {
  if (m2 > m) { s = s * __expf(m - m2) + s2; m = m2; }
  else        { s += s2 * __expf(m2 - m); }
}

__global__ void lse_reduce(const float2* __restrict__ part, const float* __restrict__ tgt,
                           const int* __restrict__ targets, float* __restrict__ nll) {
  int row = blockIdx.x;
  const float2* p = part + (size_t)row * NCHUNK;
  float m = -INFINITY, s = 0.f;
  for (int c = threadIdx.x; c < NCHUNK; c += blockDim.x) {
    float2 v = p[c];
    merge_ms(m, s, v.x, v.y);
  }
  #pragma unroll
  for (int d = 1; d < 64; d <<= 1) {
    float m2 = __shfl_xor(m, d), s2 = __shfl_xor(s, d);
    merge_ms(m, s, m2, s2);
  }
  __shared__ float sm[4], ss[4];
  int wid = threadIdx.x >> 6, lane = threadIdx.x & 63;
  if (lane == 0) { sm[wid] = m; ss[wid] = s; }
  __syncthreads();
  if (threadIdx.x == 0) {
    #pragma unroll
    for (int w2 = 1; w2 < 4; ++w2) merge_ms(m, s, sm[w2], ss[w2]);
    int t = targets[row];
    float out = 0.f;
    if (t != IGNORE_INDEX) out = m + logf(s) - tgt[row];
    nll[row] = out;
  }
}

// ---------------- final scalar: sum(nll)/count ----------------
__global__ void final_kernel(const float* __restrict__ nll, const int* __restrict__ targets,
                             float* __restrict__ out) {
  float sum = 0.f, cnt = 0.f;
  for (int i = threadIdx.x; i < Mrows; i += 64) {
    sum += nll[i];
    cnt += (targets[i] != IGNORE_INDEX) ? 1.f : 0.f;
  }
  #pragma unroll
  for (int d = 1; d < 64; d <<= 1) {
    sum += __shfl_xor(sum, d);
    cnt += __shfl_xor(cnt, d);
  }
  if (threadIdx.x == 0)
    out[0] = (cnt == 0.f) ? sum : sum / fmaxf(cnt, 1.f);
}

extern "C" void kernel_launch(void* const* d_in, const int* in_sizes, int n_in,
                              void* d_out, int out_size, void* d_ws, size_t ws_size,
                              hipStream_t stream) {
  const float* hidden = (const float*)d_in[0];   // [2,1024,1024] f32
  const float* weight = (const float*)d_in[1];   // [128000,1024] f32
  const int* targets  = (const int*)d_in[2];     // [2,1024] i32
  float* out = (float*)d_out;

  char* ws = (char*)d_ws;
  size_t off = 0;
  uchar* w8 = (uchar*)(ws + off); off += (size_t)Vc * Dc;                  // 128 MB
  uchar* h8 = (uchar*)(ws + off); off += (size_t)Mrows * Dc;               // 2 MB
  float2* part = (float2*)(ws + off); off += (size_t)Mrows * NCHUNK * sizeof(float2); // 32 MB
  float* tgt = (float*)(ws + off); off += Mrows * sizeof(float);
  float* nll = (float*)(ws + off); off += Mrows * sizeof(float);
  (void)ws_size; (void)in_sizes; (void)n_in; (void)out_size;

  cast_f32_fp8<<<2048, 256, 0, stream>>>(weight, (uchar4*)w8, (size_t)Vc * Dc / 4);
  cast_f32_fp8<<<256, 256, 0, stream>>>(hidden, (uchar4*)h8, (size_t)Mrows * Dc / 4);
  tgt_kernel<<<Mrows / 4, 256, 0, stream>>>(hidden, weight, targets, tgt);

  gemm_lse_fp8<<<8000, 512, 0, stream>>>(h8, w8, part);  // mb=bid&15, nb=bid>>4

  lse_reduce<<<Mrows, 256, 0, stream>>>(part, tgt, targets, nll);
  final_kernel<<<1, 64, 0, stream>>>(nll, targets, out);
}

// Round 18
// 631.874 us; speedup vs baseline: 1.2199x; 1.0151x over previous
//
#include <hip/hip_runtime.h>
#include <hip/hip_bf16.h>
#include <hip/hip_fp8.h>
#include <math.h>

#define IGNORE_INDEX (-100)

static constexpr int Dc = 1024, Vc = 128000;
static constexpr int Mrows = 2048;        // B*S
static constexpr int Kdim = 1024;
static constexpr int BK = 32;             // fp8: 32 elems = 32 B rows
static constexpr int NT = Kdim / BK;      // 32 K-tiles
static constexpr int NCHUNK = Vc / 64;    // 2000 partial chunks per row

typedef float f32x4_t __attribute__((ext_vector_type(4)));

// ------- cast fp32 -> fp8 e4m3 with PRE-SWIZZLED layout (8B granularity) -----
// Each thread emits one 8B slot. Within every 32B k-group of a row, slot s is
// stored at position s ^ ((row>>2)&3). This bakes the LDS bank swizzle into
// the global buffer, so the GEMM's global_load_lds can stay 16B-linear while
// ds_read_b64 achieves all-32-banks-per-16-lane-group (conflict-free; R17's
// 16B-granular swizzle left a 2-way -> +4cyc/read, 19% of kernel).
__global__ void cast_f32_fp8_swz(const float* __restrict__ in, uchar* __restrict__ out,
                                 size_t n8) {
  size_t i = (size_t)blockIdx.x * blockDim.x + threadIdx.x;
  size_t stride = (size_t)gridDim.x * blockDim.x;
  for (; i < n8; i += stride) {
    size_t byte0 = i * 8;                 // logical fp8 byte index (slot-aligned)
    size_t row = byte0 >> 10;             // 1024 B per K-row
    int s = (int)(byte0 >> 3) & 3;        // slot within 32B group
    int sw = s ^ ((int)(row >> 2) & 3);
    size_t obyte = (byte0 & ~(size_t)31) | ((size_t)sw << 3);
    float4 v0 = *reinterpret_cast<const float4*>(in + byte0);
    float4 v1 = *reinterpret_cast<const float4*>(in + byte0 + 4);
    union { uchar b[8]; unsigned long long u; } p;
    p.b[0] = __hip_fp8_e4m3(v0.x).__x; p.b[1] = __hip_fp8_e4m3(v0.y).__x;
    p.b[2] = __hip_fp8_e4m3(v0.z).__x; p.b[3] = __hip_fp8_e4m3(v0.w).__x;
    p.b[4] = __hip_fp8_e4m3(v1.x).__x; p.b[5] = __hip_fp8_e4m3(v1.y).__x;
    p.b[6] = __hip_fp8_e4m3(v1.z).__x; p.b[7] = __hip_fp8_e4m3(v1.w).__x;
    *reinterpret_cast<unsigned long long*>(out + obyte) = p.u;
  }
}

// ---------------- target logits: fp32 dot(hidden[r], weight[t[r]]) — exact ----
__global__ void tgt_kernel(const float* __restrict__ hidden, const float* __restrict__ weight,
                           const int* __restrict__ targets, float* __restrict__ tgt) {
  int row = blockIdx.x * 4 + (threadIdx.x >> 6);
  int lane = threadIdx.x & 63;
  if (row >= Mrows) return;
  int t = targets[row];
  float sum = 0.f;
  if (t != IGNORE_INDEX) {
    const float* h = hidden + (size_t)row * Kdim;
    const float* wv = weight + (size_t)t * Kdim;
    for (int k = lane * 4; k < Kdim; k += 64 * 4) {
      float4 a = *reinterpret_cast<const float4*>(h + k);
      float4 b = *reinterpret_cast<const float4*>(wv + k);
      sum += a.x * b.x + a.y * b.y + a.z * b.z + a.w * b.w;
    }
  }
  #pragma unroll
  for (int d = 1; d < 64; d <<= 1) sum += __shfl_xor(sum, d);
  if (lane == 0) tgt[row] = sum;
}

// -- 128x256 8-wave 2-BLOCK/CU ring-3 FP8 GEMM + fused partial LSE -----------
// R17 lesson: 16B-granular swizzle leaves ds_read_b64 2-way (+4cyc/read,
// SQ_LDS_BANK_CONFLICT 6.55e7 = 19% of kernel). Full fix needs 8B-granular
// slot' = slot ^ ((row>>2)&3); global_load_lds can't source-permute 8B, so
// the CAST kernel pre-swizzles the global buffer (above). Staging here is
// 16B-LINEAR; reads use the 8B-swizzled koff:
//   addr/8 mod 16 = 4*(l15&3) + (l16 ^ ((l15>>2)&3))  -> bijective over the
// 16-lane group -> 32 distinct banks -> conflict-free.
// Ring-3 + uniform vmcnt(2) (R8 rule: wave-uniform counts + identical issue
// order + in-order retirement). fp8 MFMA path validated R16/R17 (absmax~0).
#define MFMA_FP8(A, B, C) __builtin_amdgcn_mfma_f32_16x16x32_fp8_fp8((A), (B), (C), 0, 0, 0)
#define GLDS(g, l) __builtin_amdgcn_global_load_lds( \
    (const __attribute__((address_space(1))) void*)(g), \
    (__attribute__((address_space(3))) void*)(l), 16, 0, 0)

__global__ __launch_bounds__(512, 4) void gemm_lse_fp8(const uchar* __restrict__ A8,
                                                       const uchar* __restrict__ B8,
                                                       float2* __restrict__ part) {
  __shared__ uchar lds[3][12288];      // [ring][A(128x32B)=4KB | B(256x32B)=8KB]
  const int tid = threadIdx.x;
  const int wid = tid >> 6, lane = tid & 63;
  const int wr = wid >> 2, wc = wid & 3;        // 2M x 4N wave grid, wave = 64x64 out
  const int l15 = lane & 15, l16 = lane >> 4;
  const int bid = blockIdx.x;
  const int mb = bid & 15;             // 16 M-blocks share one B panel
  const int nb = bid >> 4;             // 0..499

  // staging (LINEAR 16B chunks; data pre-swizzled by cast kernel).
  const int ca = tid & 255;            // A chunk (duplicated across tid>=256: benign WAW)
  const uchar* gA = A8 + (size_t)(mb * 128) * 1024;
  const uchar* gB = B8 + (size_t)(nb * 256) * 1024;
  const uchar* sgA = gA + (size_t)(ca >> 1) * 1024 + (ca & 1) * 16;
  const uchar* sgB = gB + (size_t)(tid >> 1) * 1024 + (tid & 1) * 16;

  // read-side 8B-swizzled offset: slot' = l16 ^ ((row>>2)&3); frag row bases
  // are multiples of 16 -> (row>>2)&3 = (l15>>2)&3 per lane.
  const int koff = ((l16 ^ ((l15 >> 2) & 3)) << 3);
  const int aBase = (wr * 64 + l15) * 32 + koff;   // + mi*512 per frag
  const int bBase = (wc * 64 + l15) * 32 + koff;   // + ni*512 (B region +4096)

  f32x4_t acc[4][4];
  #pragma unroll
  for (int i = 0; i < 4; ++i)
    #pragma unroll
    for (int j = 0; j < 4; ++j)
      acc[i][j] = (f32x4_t){0.f, 0.f, 0.f, 0.f};

  #define STAGE(bufp, k0) do { \
    GLDS(sgA + (k0), (bufp) + ca * 16); \
    GLDS(sgB + (k0), (bufp) + 4096 + tid * 16); \
  } while (0)

  // prologue: tiles 0,1 staged; vmcnt(2) -> tile0's 2 loads retired
  STAGE(lds[0], 0);
  STAGE(lds[1], BK);
  asm volatile("s_waitcnt vmcnt(2)" ::: "memory");
  __builtin_amdgcn_s_barrier();

  int cur = 0;
  for (int t = 0; t < NT; ++t) {
    if (t + 2 < NT) {
      int stg = cur + 2; if (stg >= 3) stg -= 3;
      STAGE(lds[stg], (t + 2) * BK);
    }
    const uchar* Ar = lds[cur];
    const uchar* Br = lds[cur] + 4096;
    long a[4], b[4];
    #pragma unroll
    for (int mi = 0; mi < 4; ++mi)
      a[mi] = *reinterpret_cast<const long*>(Ar + aBase + mi * 512);
    #pragma unroll
    for (int ni = 0; ni < 4; ++ni)
      b[ni] = *reinterpret_cast<const long*>(Br + bBase + ni * 512);
    __builtin_amdgcn_s_setprio(1);
    #pragma unroll
    for (int mi = 0; mi < 4; ++mi)
      #pragma unroll
      for (int ni = 0; ni < 4; ++ni)
        acc[mi][ni] = MFMA_FP8(a[mi], b[ni], acc[mi][ni]);
    __builtin_amdgcn_s_setprio(0);
    if (t + 1 < NT) {
      if (t + 2 < NT) asm volatile("s_waitcnt vmcnt(2)" ::: "memory");
      else            asm volatile("s_waitcnt vmcnt(0)" ::: "memory");
      __builtin_amdgcn_s_barrier();
    }
    cur = cur + 1; if (cur >= 3) cur = 0;
  }
  #undef STAGE

  // fused partial-LSE epilogue. acc[mi][ni][j]: row = wr*64+mi*16+l16*4+j,
  // col = wc*64+ni*16+l15 (m89 C/D layout; dtype-independent m121-128)
  const int chunk = nb * 4 + wc;
  #pragma unroll
  for (int mi = 0; mi < 4; ++mi) {
    #pragma unroll
    for (int j = 0; j < 4; ++j) {
      float v0 = acc[mi][0][j], v1 = acc[mi][1][j], v2 = acc[mi][2][j], v3 = acc[mi][3][j];
      float mloc = fmaxf(fmaxf(v0, v1), fmaxf(v2, v3));
      #pragma unroll
      for (int d = 1; d < 16; d <<= 1) mloc = fmaxf(mloc, __shfl_xor(mloc, d));
      float sloc = __expf(v0 - mloc) + __expf(v1 - mloc) +
                   __expf(v2 - mloc) + __expf(v3 - mloc);
      #pragma unroll
      for (int d = 1; d < 16; d <<= 1) sloc += __shfl_xor(sloc, d);
      if (l15 == 0) {
        int grow = mb * 128 + wr * 64 + mi * 16 + l16 * 4 + j;
        part[(size_t)grow * NCHUNK + chunk] = make_float2(mloc, sloc);
      }
    }
  }
}

// ---------------- per-row merge of partials -> nll[row] ----------------
__device__ __forceinline__ void merge_ms(float& m, float& s, float m2, float s2) {
  if (m2 > m) { s = s * __expf(m - m2) + s2; m = m2; }
  else        { s += s2 * __expf(m2 - m); }
}

__global__ void lse_reduce(const float2* __restrict__ part, const float* __restrict__ tgt,
                           const int* __restrict__ targets, float* __restrict__ nll) {
  int row = blockIdx.x;
  const float2* p = part + (size_t)row * NCHUNK;
  float m = -INFINITY, s = 0.f;
  for (int c = threadIdx.x; c < NCHUNK; c += blockDim.x) {
    float2 v = p[c];
    merge_ms(m, s, v.x, v.y);
  }
  #pragma unroll
  for (int d = 1; d < 64; d <<= 1) {
    float m2 = __shfl_xor(m, d), s2 = __shfl_xor(s, d);
    merge_ms(m, s, m2, s2);
  }
  __shared__ float sm[4], ss[4];
  int wid = threadIdx.x >> 6, lane = threadIdx.x & 63;
  if (lane == 0) { sm[wid] = m; ss[wid] = s; }
  __syncthreads();
  if (threadIdx.x == 0) {
    #pragma unroll
    for (int w2 = 1; w2 < 4; ++w2) merge_ms(m, s, sm[w2], ss[w2]);
    int t = targets[row];
    float out = 0.f;
    if (t != IGNORE_INDEX) out = m + logf(s) - tgt[row];
    nll[row] = out;
  }
}

// ---------------- final scalar: sum(nll)/count ----------------
__global__ void final_kernel(const float* __restrict__ nll, const int* __restrict__ targets,
                             float* __restrict__ out) {
  float sum = 0.f, cnt = 0.f;
  for (int i = threadIdx.x; i < Mrows; i += 64) {
    sum += nll[i];
    cnt += (targets[i] != IGNORE_INDEX) ? 1.f : 0.f;
  }
  #pragma unroll
  for (int d = 1; d < 64; d <<= 1) {
    sum += __shfl_xor(sum, d);
    cnt += __shfl_xor(cnt, d);
  }
  if (threadIdx.x == 0)
    out[0] = (cnt == 0.f) ? sum : sum / fmaxf(cnt, 1.f);
}

extern "C" void kernel_launch(void* const* d_in, const int* in_sizes, int n_in,
                              void* d_out, int out_size, void* d_ws, size_t ws_size,
                              hipStream_t stream) {
  const float* hidden = (const float*)d_in[0];   // [2,1024,1024] f32
  const float* weight = (const float*)d_in[1];   // [128000,1024] f32
  const int* targets  = (const int*)d_in[2];     // [2,1024] i32
  float* out = (float*)d_out;

  char* ws = (char*)d_ws;
  size_t off = 0;
  uchar* w8 = (uchar*)(ws + off); off += (size_t)Vc * Dc;                  // 128 MB
  uchar* h8 = (uchar*)(ws + off); off += (size_t)Mrows * Dc;               // 2 MB
  float2* part = (float2*)(ws + off); off += (size_t)Mrows * NCHUNK * sizeof(float2); // 32 MB
  float* tgt = (float*)(ws + off); off += Mrows * sizeof(float);
  float* nll = (float*)(ws + off); off += Mrows * sizeof(float);
  (void)ws_size; (void)in_sizes; (void)n_in; (void)out_size;

  cast_f32_fp8_swz<<<2048, 256, 0, stream>>>(weight, w8, (size_t)Vc * Dc / 8);
  cast_f32_fp8_swz<<<256, 256, 0, stream>>>(hidden, h8, (size_t)Mrows * Dc / 8);
  tgt_kernel<<<Mrows / 4, 256, 0, stream>>>(hidden, weight, targets, tgt);

  gemm_lse_fp8<<<8000, 512, 0, stream>>>(h8, w8, part);  // mb=bid&15, nb=bid>>4

  lse_reduce<<<Mrows, 256, 0, stream>>>(part, tgt, targets, nll);
  final_kernel<<<1, 64, 0, stream>>>(nll, targets, out);
}